// Round 1
// baseline (555.133 us; speedup 1.0000x reference)
//
#include <hip/hip_runtime.h>
#include <hip/hip_bf16.h>

#define HIDDEN 8192
#define NHEADS 64
#define NKV 8
#define HD 128
#define BATCH 32
#define PADLEN 2048

// ---------------------------------------------------------------------------
// Skinny GEMM: out[32][N] += X[32][K] @ W[K][N]   (K-split via blockIdx.y,
// partials combined with f32 atomicAdd; out must be pre-zeroed).
// Block: 256 threads, each owns 2 output columns for all 32 batch rows.
// ---------------------------------------------------------------------------
#define KC 256
__global__ __launch_bounds__(256) void gemm_skinny(const float* __restrict__ X,
                                                   const float* __restrict__ W,
                                                   float* __restrict__ out,
                                                   int K, int N) {
    __shared__ float xs[BATCH][KC];
    const int tid = threadIdx.x;
    const int cb = blockIdx.x, kb = blockIdx.y;
    const int k0 = kb * KC;

    // stage x chunk: 32 rows x 256 cols = 32 KB, float4 coalesced
    for (int i = tid; i < BATCH * (KC / 4); i += 256) {
        int b = i >> 6;          // KC/4 == 64
        int k4 = i & 63;
        *(float4*)&xs[b][k4 * 4] = *(const float4*)(X + (size_t)b * K + k0 + k4 * 4);
    }
    __syncthreads();

    const int c0 = cb * 512 + tid * 2;
    float2 acc[BATCH];
#pragma unroll
    for (int b = 0; b < BATCH; ++b) acc[b] = make_float2(0.f, 0.f);

    const float* wp = W + (size_t)k0 * N + c0;
    for (int kk = 0; kk < KC; kk += 4) {
        // 4 weight rows (float2 each)
        float2 w0 = *(const float2*)(wp);
        float2 w1 = *(const float2*)(wp + N);
        float2 w2 = *(const float2*)(wp + 2 * (size_t)N);
        float2 w3 = *(const float2*)(wp + 3 * (size_t)N);
        wp += 4 * (size_t)N;
#pragma unroll
        for (int b = 0; b < BATCH; ++b) {
            float4 xv = *(const float4*)&xs[b][kk];   // LDS b128 broadcast
            acc[b].x = fmaf(xv.x, w0.x, acc[b].x);
            acc[b].y = fmaf(xv.x, w0.y, acc[b].y);
            acc[b].x = fmaf(xv.y, w1.x, acc[b].x);
            acc[b].y = fmaf(xv.y, w1.y, acc[b].y);
            acc[b].x = fmaf(xv.z, w2.x, acc[b].x);
            acc[b].y = fmaf(xv.z, w2.y, acc[b].y);
            acc[b].x = fmaf(xv.w, w3.x, acc[b].x);
            acc[b].y = fmaf(xv.w, w3.y, acc[b].y);
        }
    }
#pragma unroll
    for (int b = 0; b < BATCH; ++b) {
        atomicAdd(out + (size_t)b * N + c0,     acc[b].x);
        atomicAdd(out + (size_t)b * N + c0 + 1, acc[b].y);
    }
}

// ---------------------------------------------------------------------------
// Rotary: rows 0..2047 = q rows (32*64), rows 2048..2303 = k rows (32*8).
// row_out[j] = sum_d row_in[d] * rot[d][j]
// ---------------------------------------------------------------------------
#define RROWS 16
__global__ __launch_bounds__(128) void rotary_all(const float* __restrict__ qin,
                                                  const float* __restrict__ kin,
                                                  const float* __restrict__ rot,
                                                  float* __restrict__ qout,
                                                  float* __restrict__ kout) {
    __shared__ float rows[RROWS][HD];
    const int tid = threadIdx.x;
    const int row0 = blockIdx.x * RROWS;

    for (int i = tid; i < RROWS * (HD / 4); i += 128) {
        int r = i >> 5;
        int d4 = i & 31;
        int gr = row0 + r;
        const float* src = (gr < BATCH * NHEADS)
                               ? (qin + (size_t)gr * HD)
                               : (kin + (size_t)(gr - BATCH * NHEADS) * HD);
        *(float4*)&rows[r][d4 * 4] = *(const float4*)(src + d4 * 4);
    }
    __syncthreads();

    float acc[RROWS];
#pragma unroll
    for (int r = 0; r < RROWS; ++r) acc[r] = 0.f;

    for (int d4 = 0; d4 < HD; d4 += 4) {
        float r0 = rot[(size_t)(d4 + 0) * HD + tid];
        float r1 = rot[(size_t)(d4 + 1) * HD + tid];
        float r2 = rot[(size_t)(d4 + 2) * HD + tid];
        float r3 = rot[(size_t)(d4 + 3) * HD + tid];
#pragma unroll
        for (int r = 0; r < RROWS; ++r) {
            float4 xv = *(const float4*)&rows[r][d4];
            acc[r] = fmaf(xv.x, r0, acc[r]);
            acc[r] = fmaf(xv.y, r1, acc[r]);
            acc[r] = fmaf(xv.z, r2, acc[r]);
            acc[r] = fmaf(xv.w, r3, acc[r]);
        }
    }
#pragma unroll
    for (int r = 0; r < RROWS; ++r) {
        int gr = row0 + r;
        float* dst = (gr < BATCH * NHEADS)
                         ? (qout + (size_t)gr * HD)
                         : (kout + (size_t)(gr - BATCH * NHEADS) * HD);
        dst[tid] = acc[r];
    }
}

// ---------------------------------------------------------------------------
// Flash-decode attention. Grid: 256 blocks = (b, kv). Block: 512 thr = 8 waves,
// wave w handles q-head kv*8+w. Tile = 128 positions.
// K tile staged XOR-swizzled (avoids 512B-stride bank conflict on lane-owns-row
// reads); V tile staged linear (row-contiguous reads are floor-optimal).
// Position sp substitutes k_new/v_new (cache inputs are NOT mutated).
// ---------------------------------------------------------------------------
#define TILE 128
__global__ __launch_bounds__(512) void attn_decode(const float* __restrict__ qr,
                                                   const float* __restrict__ kr,
                                                   const float* __restrict__ vnew,
                                                   const float* __restrict__ kcache,
                                                   const float* __restrict__ vcache,
                                                   const int* __restrict__ sp_ptr,
                                                   float* __restrict__ attn_out) {
    __shared__ float4 k_lds[TILE][32];      // 64 KB, swizzled slots
    __shared__ float  v_lds[TILE][HD];      // 64 KB, linear
    __shared__ float  q_lds[NKV][HD];       // 4 KB (8 heads of this group)
    __shared__ float  p_lds[NKV][TILE];     // 4 KB

    const int tid = threadIdx.x;
    const int wv = tid >> 6;
    const int ln = tid & 63;
    const int b  = blockIdx.x >> 3;
    const int kv = blockIdx.x & 7;
    const int sp = sp_ptr[0];
    const float scale = 0.08838834764831845f;  // 1/sqrt(128)

    const float* kbase = kcache + (size_t)(b * NKV + kv) * PADLEN * HD;
    const float* vbase = vcache + (size_t)(b * NKV + kv) * PADLEN * HD;
    const float* knew  = kr   + (size_t)(b * NKV + kv) * HD;
    const float* vnw   = vnew + (size_t)(b * NKV + kv) * HD;

    // stage q for the 8 heads of this kv group (contiguous in qr)
    {
        const float2* src = (const float2*)(qr + (size_t)(b * NHEADS + kv * 8) * HD);
        ((float2*)q_lds)[tid] = src[tid];   // 512 float2 = 1024 floats
    }

    const int head = wv;
    float m_run = -1e30f, dpart = 0.f, acc0 = 0.f, acc1 = 0.f;
    const int nt = (sp + TILE) >> 7;        // ceil((sp+1)/128)

    for (int t = 0; t < nt; ++t) {
        const int tile0 = t << 7;
        __syncthreads();   // LDS safe to overwrite (also covers q staging at t=0)

        // ---- stage K (swizzled) + V (linear): 128 KB total, reg-staged ----
        for (int it = 0; it < 8; ++it) {
            int s = it * 512 + tid;          // 16B-slot index, 4096 total
            int r = s >> 5;                  // row 0..127
            int j = s & 31;                  // slot in row
            int gl = tile0 + r;
            const float* ksrc = (gl == sp) ? knew : (kbase + (size_t)gl * HD);
            const float* vsrc = (gl == sp) ? vnw  : (vbase + (size_t)gl * HD);
            float4 kd = *(const float4*)(ksrc + j * 4);
            float4 vd = *(const float4*)(vsrc + j * 4);
            k_lds[r][j ^ (r & 31)] = kd;
            *(float4*)&v_lds[r][j * 4] = vd;
        }
        __syncthreads();

        // ---- phase A: scores, lane owns 2 positions ----
        float s0 = 0.f, s1 = 0.f;
#pragma unroll 8
        for (int d4 = 0; d4 < 32; ++d4) {
            float4 qv = *(const float4*)&q_lds[head][d4 * 4];  // broadcast
            int sl = d4 ^ (ln & 31);
            float4 ka = k_lds[ln][sl];
            float4 kb2 = k_lds[64 + ln][sl];
            s0 = fmaf(qv.x, ka.x, s0);  s0 = fmaf(qv.y, ka.y, s0);
            s0 = fmaf(qv.z, ka.z, s0);  s0 = fmaf(qv.w, ka.w, s0);
            s1 = fmaf(qv.x, kb2.x, s1); s1 = fmaf(qv.y, kb2.y, s1);
            s1 = fmaf(qv.z, kb2.z, s1); s1 = fmaf(qv.w, kb2.w, s1);
        }
        s0 *= scale; s1 *= scale;
        int l0 = tile0 + ln, l1 = tile0 + 64 + ln;
        if (l0 > sp) s0 = -1e30f;
        if (l1 > sp) s1 = -1e30f;

        float mt = fmaxf(s0, s1);
#pragma unroll
        for (int o = 32; o > 0; o >>= 1) mt = fmaxf(mt, __shfl_xor(mt, o));
        float mnew = fmaxf(m_run, mt);
        float f = __expf(m_run - mnew);
        float p0 = (l0 > sp) ? 0.f : __expf(s0 - mnew);
        float p1 = (l1 > sp) ? 0.f : __expf(s1 - mnew);
        dpart = dpart * f + p0 + p1;
        acc0 *= f; acc1 *= f;
        m_run = mnew;
        p_lds[head][ln] = p0;
        p_lds[head][64 + ln] = p1;
        __syncthreads();

        // ---- phase B: PV, lane owns dims (2*ln, 2*ln+1) ----
#pragma unroll 4
        for (int l4 = 0; l4 < TILE / 4; ++l4) {
            float4 pv = *(const float4*)&p_lds[head][l4 * 4];  // broadcast
            float2 v0 = *(const float2*)&v_lds[l4 * 4 + 0][ln * 2];
            float2 v1 = *(const float2*)&v_lds[l4 * 4 + 1][ln * 2];
            float2 v2 = *(const float2*)&v_lds[l4 * 4 + 2][ln * 2];
            float2 v3 = *(const float2*)&v_lds[l4 * 4 + 3][ln * 2];
            acc0 = fmaf(pv.x, v0.x, acc0); acc1 = fmaf(pv.x, v0.y, acc1);
            acc0 = fmaf(pv.y, v1.x, acc0); acc1 = fmaf(pv.y, v1.y, acc1);
            acc0 = fmaf(pv.z, v2.x, acc0); acc1 = fmaf(pv.z, v2.y, acc1);
            acc0 = fmaf(pv.w, v3.x, acc0); acc1 = fmaf(pv.w, v3.y, acc1);
        }
    }

    float denom = dpart;
#pragma unroll
    for (int o = 32; o > 0; o >>= 1) denom += __shfl_xor(denom, o);
    float inv = 1.f / denom;

    float2 res = make_float2(acc0 * inv, acc1 * inv);
    *(float2*)(attn_out + ((size_t)(b * NHEADS + kv * 8 + head)) * HD + ln * 2) = res;
}

// ---------------------------------------------------------------------------
extern "C" void kernel_launch(void* const* d_in, const int* in_sizes, int n_in,
                              void* d_out, int out_size, void* d_ws, size_t ws_size,
                              hipStream_t stream) {
    const float* x   = (const float*)d_in[0];
    const float* wq  = (const float*)d_in[1];
    const float* wk  = (const float*)d_in[2];
    const float* wv  = (const float*)d_in[3];
    const float* wo  = (const float*)d_in[4];
    const float* rot = (const float*)d_in[5];
    const float* kc  = (const float*)d_in[6];
    const float* vc  = (const float*)d_in[7];
    const int*   sp  = (const int*)d_in[8];
    float* out = (float*)d_out;

    float* ws = (float*)d_ws;
    float* q_buf    = ws;                   // 32*8192
    float* k_buf    = q_buf + 262144;       // 32*1024
    float* v_buf    = k_buf + 32768;        // 32*1024
    float* qr_buf   = v_buf + 32768;        // 32*8192
    float* kr_buf   = qr_buf + 262144;      // 32*1024
    float* attn_buf = kr_buf + 32768;       // 32*8192

    // zero atomic-accumulated buffers (every call — deterministic)
    hipMemsetAsync(d_ws, 0, (size_t)(262144 + 32768 + 32768) * sizeof(float), stream);
    hipMemsetAsync(d_out, 0, (size_t)out_size * sizeof(float), stream);

    gemm_skinny<<<dim3(16, 32), 256, 0, stream>>>(x, wq, q_buf, HIDDEN, NHEADS * HD);
    gemm_skinny<<<dim3(2, 32),  256, 0, stream>>>(x, wk, k_buf, HIDDEN, NKV * HD);
    gemm_skinny<<<dim3(2, 32),  256, 0, stream>>>(x, wv, v_buf, HIDDEN, NKV * HD);
    rotary_all<<<(BATCH * NHEADS + BATCH * NKV) / RROWS, 128, 0, stream>>>(
        q_buf, k_buf, rot, qr_buf, kr_buf);
    attn_decode<<<BATCH * NKV, 512, 0, stream>>>(qr_buf, kr_buf, v_buf, kc, vc, sp, attn_buf);
    gemm_skinny<<<dim3(16, 32), 256, 0, stream>>>(attn_buf, wo, out, HIDDEN, HIDDEN);
}